// Round 7
// baseline (97.860 us; speedup 1.0000x reference)
//
#include <hip/hip_runtime.h>
#include <hip/hip_bf16.h>
#include <stdint.h>

typedef __bf16 bf16x8 __attribute__((ext_vector_type(8)));
typedef float f32x4 __attribute__((ext_vector_type(4)));

#define NQ 8192
#define NP 4096
#define DD 512
#define NT 8

#define REG_A(buf, ks) ((unsigned)((buf)*32768 + (ks)*16384))
#define REG_B(buf, ks) ((unsigned)(65536 + (buf)*32768 + (ks)*16384))

// Fused: out[n][m] = (||x_n||^2 + ||y_m||^2 - 2 x.y)/512.
// 256x256 tile, 8 waves (2M x 4N), BK=64, TWO phases per K-tile (ks=0/1,
// 32 MFMA each) => 4 barriers/K-tile (r2 had 8; model: T = 2483 + 280*phases).
// Staging: fp32 global -> 8 f32x4 regs (issued phase p) -> cvt bf16 + fp32
// norm FMAs + ds_write_b128 (drained phase p+1). Compiler-derived waitcnts.
// LDS 128KB bf16 panels (same layout/swizzle as r2) + 2KB norms.
// Ledger: region (buf,ks) read at phase start, reader self-drains at its
// lgkm(0) before MFMA; overwrite happens >=1 phase later in the pre-barrier
// segment (after the reader phase's end-BAR); write drains at writer's
// lgkm(0) >=2 barriers before next read. Prologue stages tiles 0,1 sync.
__global__ __launch_bounds__(512, 2) void fused_dist_kernel(
    const float* __restrict__ X, const float* __restrict__ Y,
    float* __restrict__ out) {
  __shared__ __align__(128) unsigned char lds[133120];
  float* xs_l = (float*)(lds + 131072);
  float* ys_l = (float*)(lds + 132096);

  const int tid = threadIdx.x;
  const int wave = tid >> 6;
  const int lane = tid & 63;
  const int fr = lane & 15, fq = lane >> 4;
  const int wr = wave >> 2;  // 0..1: rows wr*128..+128
  const int wc = wave & 3;   // 0..3: cols wc*64..+64

  // XCD swizzle: 512 blocks, 64 contiguous wgids per XCD (bijective).
  const int bid = blockIdx.x;
  const int wgid = (bid & 7) * 64 + (bid >> 3);
  const int tileN = wgid & 15;
  const int tileM = wgid >> 4;
  const int brow = tileM * 256;
  const int bcol = tileN * 256;

  // Staging geometry: linear LDS dst byte P (per lane), fp32 source element
  // from inverse-swizzled L(P). Two chunks per thread per half-tile.
  const unsigned Pw0 = (unsigned)(wave * 2048 + lane * 16);
  const unsigned Pw1 = Pw0 + 1024u;
  const unsigned L0 = Pw0 ^ (((Pw0 >> 7) & 3u) << 4);
  const unsigned L1 = Pw1 ^ (((Pw1 >> 7) & 3u) << 4);
  const unsigned aoff0 = (unsigned)(brow + (int)(L0 >> 6)) * DD + ((L0 & 63u) >> 1);
  const unsigned aoff1 = (unsigned)(brow + (int)(L1 >> 6)) * DD + ((L1 & 63u) >> 1);
  const unsigned boff0 = (unsigned)(bcol + (int)(L0 >> 6)) * DD + ((L0 & 63u) >> 1);
  const unsigned boff1 = (unsigned)(bcol + (int)(L1 >> 6)) * DD + ((L1 & 63u) >> 1);

  // fragment read offsets (swizzled)
  const unsigned cswz = (unsigned)((fq ^ ((fr >> 1) & 3)) << 4);
  const unsigned rA = (unsigned)((wr * 128 + fr) * 64) + cswz;  // + m*1024
  const unsigned rB = (unsigned)((wc * 64 + fr) * 64) + cswz;   // + n*1024

  f32x4 acc[8][4] = {};
  float nA0 = 0.f, nA1 = 0.f, nB0 = 0.f, nB1 = 0.f;
  f32x4 pA0, pA1, pA2, pA3, pB0, pB1, pB2, pB3;

  auto issueX = [&](int t, int ks) {
    const unsigned k = (unsigned)(t * 64 + ks * 32);
    pA0 = *(const f32x4*)(X + aoff0 + k);
    pA1 = *(const f32x4*)(X + aoff0 + k + 4);
    pA2 = *(const f32x4*)(X + aoff1 + k);
    pA3 = *(const f32x4*)(X + aoff1 + k + 4);
  };
  auto issueY = [&](int t, int ks) {
    const unsigned k = (unsigned)(t * 64 + ks * 32);
    pB0 = *(const f32x4*)(Y + boff0 + k);
    pB1 = *(const f32x4*)(Y + boff0 + k + 4);
    pB2 = *(const f32x4*)(Y + boff1 + k);
    pB3 = *(const f32x4*)(Y + boff1 + k + 4);
  };
  auto drainA = [&](unsigned base) {
    nA0 += pA0[0]*pA0[0] + pA0[1]*pA0[1] + pA0[2]*pA0[2] + pA0[3]*pA0[3]
         + pA1[0]*pA1[0] + pA1[1]*pA1[1] + pA1[2]*pA1[2] + pA1[3]*pA1[3];
    nA1 += pA2[0]*pA2[0] + pA2[1]*pA2[1] + pA2[2]*pA2[2] + pA2[3]*pA2[3]
         + pA3[0]*pA3[0] + pA3[1]*pA3[1] + pA3[2]*pA3[2] + pA3[3]*pA3[3];
    bf16x8 w0, w1;
    w0[0]=(__bf16)pA0[0]; w0[1]=(__bf16)pA0[1]; w0[2]=(__bf16)pA0[2]; w0[3]=(__bf16)pA0[3];
    w0[4]=(__bf16)pA1[0]; w0[5]=(__bf16)pA1[1]; w0[6]=(__bf16)pA1[2]; w0[7]=(__bf16)pA1[3];
    w1[0]=(__bf16)pA2[0]; w1[1]=(__bf16)pA2[1]; w1[2]=(__bf16)pA2[2]; w1[3]=(__bf16)pA2[3];
    w1[4]=(__bf16)pA3[0]; w1[5]=(__bf16)pA3[1]; w1[6]=(__bf16)pA3[2]; w1[7]=(__bf16)pA3[3];
    *(bf16x8*)(lds + base + Pw0) = w0;
    *(bf16x8*)(lds + base + Pw1) = w1;
  };
  auto drainB = [&](unsigned base) {
    nB0 += pB0[0]*pB0[0] + pB0[1]*pB0[1] + pB0[2]*pB0[2] + pB0[3]*pB0[3]
         + pB1[0]*pB1[0] + pB1[1]*pB1[1] + pB1[2]*pB1[2] + pB1[3]*pB1[3];
    nB1 += pB2[0]*pB2[0] + pB2[1]*pB2[1] + pB2[2]*pB2[2] + pB2[3]*pB2[3]
         + pB3[0]*pB3[0] + pB3[1]*pB3[1] + pB3[2]*pB3[2] + pB3[3]*pB3[3];
    bf16x8 w0, w1;
    w0[0]=(__bf16)pB0[0]; w0[1]=(__bf16)pB0[1]; w0[2]=(__bf16)pB0[2]; w0[3]=(__bf16)pB0[3];
    w0[4]=(__bf16)pB1[0]; w0[5]=(__bf16)pB1[1]; w0[6]=(__bf16)pB1[2]; w0[7]=(__bf16)pB1[3];
    w1[0]=(__bf16)pB2[0]; w1[1]=(__bf16)pB2[1]; w1[2]=(__bf16)pB2[2]; w1[3]=(__bf16)pB2[3];
    w1[4]=(__bf16)pB3[0]; w1[5]=(__bf16)pB3[1]; w1[6]=(__bf16)pB3[2]; w1[7]=(__bf16)pB3[3];
    *(bf16x8*)(lds + base + Pw0) = w0;
    *(bf16x8*)(lds + base + Pw1) = w1;
  };

  // ---- prologue: stage tiles 0 and 1 fully (sync), norms included ----
  #pragma unroll
  for (int t = 0; t < 2; ++t)
    #pragma unroll
    for (int ks = 0; ks < 2; ++ks) {
      issueX(t, ks);
      issueY(t, ks);
      drainA(REG_A(t, ks));
      drainB(REG_B(t, ks));
    }
  asm volatile("s_waitcnt lgkmcnt(0)" ::: "memory");
  __builtin_amdgcn_s_barrier();

  bf16x8 a[8], b[4];

  #pragma unroll 2
  for (int g = 0; g < NT; ++g) {
    const int buf = g & 1;

    // ---- PhA: ks=0, all n; drain {A1,B1}(g+1); issue {A0,B0}(g+2) ----
    #pragma unroll
    for (int m = 0; m < 8; ++m)
      a[m] = *(const bf16x8*)(lds + REG_A(buf, 0) + rA + (unsigned)m * 1024u);
    #pragma unroll
    for (int n = 0; n < 4; ++n)
      b[n] = *(const bf16x8*)(lds + REG_B(buf, 0) + rB + (unsigned)n * 1024u);
    if (g >= 1 && g < 7) {
      drainA(REG_A(buf ^ 1, 1));
      drainB(REG_B(buf ^ 1, 1));
    }
    if (g + 2 < NT) {
      issueX(g + 2, 0);
      issueY(g + 2, 0);
    }
    __builtin_amdgcn_s_barrier();
    asm volatile("s_waitcnt lgkmcnt(0)" ::: "memory");
    __builtin_amdgcn_sched_barrier(0);
    __builtin_amdgcn_s_setprio(1);
    #pragma unroll
    for (int m = 0; m < 8; ++m)
      #pragma unroll
      for (int n = 0; n < 4; ++n)
        acc[m][n] = __builtin_amdgcn_mfma_f32_16x16x32_bf16(a[m], b[n],
                                                            acc[m][n], 0, 0, 0);
    __builtin_amdgcn_s_setprio(0);
    __builtin_amdgcn_s_barrier();

    // ---- PhB: ks=1, all n; drain {A0,B0}(g+2); issue {A1,B1}(g+2) ----
    #pragma unroll
    for (int m = 0; m < 8; ++m)
      a[m] = *(const bf16x8*)(lds + REG_A(buf, 1) + rA + (unsigned)m * 1024u);
    #pragma unroll
    for (int n = 0; n < 4; ++n)
      b[n] = *(const bf16x8*)(lds + REG_B(buf, 1) + rB + (unsigned)n * 1024u);
    if (g + 2 < NT) {
      drainA(REG_A(buf, 0));
      drainB(REG_B(buf, 0));
      issueX(g + 2, 1);
      issueY(g + 2, 1);
    }
    __builtin_amdgcn_s_barrier();
    asm volatile("s_waitcnt lgkmcnt(0)" ::: "memory");
    __builtin_amdgcn_sched_barrier(0);
    __builtin_amdgcn_s_setprio(1);
    #pragma unroll
    for (int m = 0; m < 8; ++m)
      #pragma unroll
      for (int n = 0; n < 4; ++n)
        acc[m][n] = __builtin_amdgcn_mfma_f32_16x16x32_bf16(a[m], b[n],
                                                            acc[m][n], 0, 0, 0);
    __builtin_amdgcn_s_setprio(0);
    __builtin_amdgcn_s_barrier();
  }

  // ---- norms: 4-lane row groups -> LDS publish ----
  nA0 += __shfl_xor(nA0, 1, 64); nA0 += __shfl_xor(nA0, 2, 64);
  nA1 += __shfl_xor(nA1, 1, 64); nA1 += __shfl_xor(nA1, 2, 64);
  nB0 += __shfl_xor(nB0, 1, 64); nB0 += __shfl_xor(nB0, 2, 64);
  nB1 += __shfl_xor(nB1, 1, 64); nB1 += __shfl_xor(nB1, 2, 64);
  if ((lane & 3) == 0) {
    const int j = lane >> 2;
    xs_l[wave * 32 + j] = nA0;
    xs_l[wave * 32 + 16 + j] = nA1;
    ys_l[wave * 32 + j] = nB0;
    ys_l[wave * 32 + 16 + j] = nB1;
  }
  asm volatile("s_waitcnt lgkmcnt(0)" ::: "memory");
  __builtin_amdgcn_s_barrier();

  // ---- epilogue: out = (||x||^2 + ||y||^2 - 2*dot) / 512 ----
  float ysv[4];
  #pragma unroll
  for (int n = 0; n < 4; ++n) ysv[n] = ys_l[wc * 64 + n * 16 + fr];

  #pragma unroll
  for (int m = 0; m < 8; ++m) {
    const int rl = wr * 128 + m * 16 + fq * 4;
    float xsv[4];
    #pragma unroll
    for (int r = 0; r < 4; ++r) xsv[r] = xs_l[rl + r];
    #pragma unroll
    for (int n = 0; n < 4; ++n) {
      const int col = bcol + wc * 64 + n * 16 + fr;
      #pragma unroll
      for (int r = 0; r < 4; ++r) {
        out[(size_t)(brow + rl + r) * NP + col] =
            (xsv[r] + ysv[n] - 2.0f * acc[m][n][r]) * (1.0f / 512.0f);
      }
    }
  }
}

extern "C" void kernel_launch(void* const* d_in, const int* in_sizes, int n_in,
                              void* d_out, int out_size, void* d_ws, size_t ws_size,
                              hipStream_t stream) {
  const float* X = (const float*)d_in[0];  // z_queries (8192, 512)
  const float* Y = (const float*)d_in[1];  // class_prototypes (4096, 512)
  float* out = (float*)d_out;              // (8192, 4096)
  fused_dist_kernel<<<512, 512, 0, stream>>>(X, Y, out);
}

// Round 8
// 97.688 us; speedup vs baseline: 1.0018x; 1.0018x over previous
//
#include <hip/hip_runtime.h>
#include <hip/hip_bf16.h>
#include <stdint.h>

typedef __bf16 bf16x8 __attribute__((ext_vector_type(8)));
typedef float f32x4 __attribute__((ext_vector_type(4)));

#define NQ 8192
#define NP 4096
#define DD 512
#define NT 8

#define REG_A(buf, ks) ((unsigned)((buf)*32768 + (ks)*16384))
#define REG_B(buf, ks) ((unsigned)(65536 + (buf)*32768 + (ks)*16384))

// Fused: out[n][m] = (||x_n||^2 + ||y_m||^2 - 2 x.y)/512.
// 256x256 tile, 8 waves (2M x 4N), BK=64, TWO phases per K-tile (ks=0/1,
// 32 MFMA each) => 4 barriers/K-tile. Staging: fp32 global -> 8 f32x4 regs
// (issued phase p) -> cvt bf16 + fp32 norm FMAs + ds_write_b128 (drained
// phase p+1..p+2). Compiler-derived waitcnts (register-visible deps).
// LDS 128KB bf16 panels + 2KB norms.
//
// ROUND 8 CHANGE (only): __launch_bounds__(512, 2) -> (512, 1).
// r4/r7 counters showed VGPR_Count=128 (cap for 4 waves/SIMD) -> acc(128)
// + frags(48) + pending(32) spilled to scratch: FETCH 92MB / WRITE 188MB
// (~110MB spill traffic), MfmaUtil 10.5%. (512,1) -> 1 block/CU -> 2
// waves/SIMD -> 256-reg cap; ~238 live fits. LDS(130KB) already implies
// 1 block/CU, so nothing is lost.
__global__ __launch_bounds__(512, 1) void fused_dist_kernel(
    const float* __restrict__ X, const float* __restrict__ Y,
    float* __restrict__ out) {
  __shared__ __align__(128) unsigned char lds[133120];
  float* xs_l = (float*)(lds + 131072);
  float* ys_l = (float*)(lds + 132096);

  const int tid = threadIdx.x;
  const int wave = tid >> 6;
  const int lane = tid & 63;
  const int fr = lane & 15, fq = lane >> 4;
  const int wr = wave >> 2;  // 0..1: rows wr*128..+128
  const int wc = wave & 3;   // 0..3: cols wc*64..+64

  // XCD swizzle: 512 blocks, 64 contiguous wgids per XCD (bijective).
  const int bid = blockIdx.x;
  const int wgid = (bid & 7) * 64 + (bid >> 3);
  const int tileN = wgid & 15;
  const int tileM = wgid >> 4;
  const int brow = tileM * 256;
  const int bcol = tileN * 256;

  // Staging geometry: linear LDS dst byte P (per lane), fp32 source element
  // from inverse-swizzled L(P). Two chunks per thread per half-tile.
  const unsigned Pw0 = (unsigned)(wave * 2048 + lane * 16);
  const unsigned Pw1 = Pw0 + 1024u;
  const unsigned L0 = Pw0 ^ (((Pw0 >> 7) & 3u) << 4);
  const unsigned L1 = Pw1 ^ (((Pw1 >> 7) & 3u) << 4);
  const unsigned aoff0 = (unsigned)(brow + (int)(L0 >> 6)) * DD + ((L0 & 63u) >> 1);
  const unsigned aoff1 = (unsigned)(brow + (int)(L1 >> 6)) * DD + ((L1 & 63u) >> 1);
  const unsigned boff0 = (unsigned)(bcol + (int)(L0 >> 6)) * DD + ((L0 & 63u) >> 1);
  const unsigned boff1 = (unsigned)(bcol + (int)(L1 >> 6)) * DD + ((L1 & 63u) >> 1);

  // fragment read offsets (swizzled)
  const unsigned cswz = (unsigned)((fq ^ ((fr >> 1) & 3)) << 4);
  const unsigned rA = (unsigned)((wr * 128 + fr) * 64) + cswz;  // + m*1024
  const unsigned rB = (unsigned)((wc * 64 + fr) * 64) + cswz;   // + n*1024

  f32x4 acc[8][4] = {};
  float nA0 = 0.f, nA1 = 0.f, nB0 = 0.f, nB1 = 0.f;
  f32x4 pA0, pA1, pA2, pA3, pB0, pB1, pB2, pB3;

  auto issueX = [&](int t, int ks) {
    const unsigned k = (unsigned)(t * 64 + ks * 32);
    pA0 = *(const f32x4*)(X + aoff0 + k);
    pA1 = *(const f32x4*)(X + aoff0 + k + 4);
    pA2 = *(const f32x4*)(X + aoff1 + k);
    pA3 = *(const f32x4*)(X + aoff1 + k + 4);
  };
  auto issueY = [&](int t, int ks) {
    const unsigned k = (unsigned)(t * 64 + ks * 32);
    pB0 = *(const f32x4*)(Y + boff0 + k);
    pB1 = *(const f32x4*)(Y + boff0 + k + 4);
    pB2 = *(const f32x4*)(Y + boff1 + k);
    pB3 = *(const f32x4*)(Y + boff1 + k + 4);
  };
  auto drainA = [&](unsigned base) {
    nA0 += pA0[0]*pA0[0] + pA0[1]*pA0[1] + pA0[2]*pA0[2] + pA0[3]*pA0[3]
         + pA1[0]*pA1[0] + pA1[1]*pA1[1] + pA1[2]*pA1[2] + pA1[3]*pA1[3];
    nA1 += pA2[0]*pA2[0] + pA2[1]*pA2[1] + pA2[2]*pA2[2] + pA2[3]*pA2[3]
         + pA3[0]*pA3[0] + pA3[1]*pA3[1] + pA3[2]*pA3[2] + pA3[3]*pA3[3];
    bf16x8 w0, w1;
    w0[0]=(__bf16)pA0[0]; w0[1]=(__bf16)pA0[1]; w0[2]=(__bf16)pA0[2]; w0[3]=(__bf16)pA0[3];
    w0[4]=(__bf16)pA1[0]; w0[5]=(__bf16)pA1[1]; w0[6]=(__bf16)pA1[2]; w0[7]=(__bf16)pA1[3];
    w1[0]=(__bf16)pA2[0]; w1[1]=(__bf16)pA2[1]; w1[2]=(__bf16)pA2[2]; w1[3]=(__bf16)pA2[3];
    w1[4]=(__bf16)pA3[0]; w1[5]=(__bf16)pA3[1]; w1[6]=(__bf16)pA3[2]; w1[7]=(__bf16)pA3[3];
    *(bf16x8*)(lds + base + Pw0) = w0;
    *(bf16x8*)(lds + base + Pw1) = w1;
  };
  auto drainB = [&](unsigned base) {
    nB0 += pB0[0]*pB0[0] + pB0[1]*pB0[1] + pB0[2]*pB0[2] + pB0[3]*pB0[3]
         + pB1[0]*pB1[0] + pB1[1]*pB1[1] + pB1[2]*pB1[2] + pB1[3]*pB1[3];
    nB1 += pB2[0]*pB2[0] + pB2[1]*pB2[1] + pB2[2]*pB2[2] + pB2[3]*pB2[3]
         + pB3[0]*pB3[0] + pB3[1]*pB3[1] + pB3[2]*pB3[2] + pB3[3]*pB3[3];
    bf16x8 w0, w1;
    w0[0]=(__bf16)pB0[0]; w0[1]=(__bf16)pB0[1]; w0[2]=(__bf16)pB0[2]; w0[3]=(__bf16)pB0[3];
    w0[4]=(__bf16)pB1[0]; w0[5]=(__bf16)pB1[1]; w0[6]=(__bf16)pB1[2]; w0[7]=(__bf16)pB1[3];
    w1[0]=(__bf16)pB2[0]; w1[1]=(__bf16)pB2[1]; w1[2]=(__bf16)pB2[2]; w1[3]=(__bf16)pB2[3];
    w1[4]=(__bf16)pB3[0]; w1[5]=(__bf16)pB3[1]; w1[6]=(__bf16)pB3[2]; w1[7]=(__bf16)pB3[3];
    *(bf16x8*)(lds + base + Pw0) = w0;
    *(bf16x8*)(lds + base + Pw1) = w1;
  };

  // ---- prologue: stage tiles 0 and 1 fully (sync), norms included ----
  #pragma unroll
  for (int t = 0; t < 2; ++t)
    #pragma unroll
    for (int ks = 0; ks < 2; ++ks) {
      issueX(t, ks);
      issueY(t, ks);
      drainA(REG_A(t, ks));
      drainB(REG_B(t, ks));
    }
  asm volatile("s_waitcnt lgkmcnt(0)" ::: "memory");
  __builtin_amdgcn_s_barrier();

  bf16x8 a[8], b[4];

  #pragma unroll 2
  for (int g = 0; g < NT; ++g) {
    const int buf = g & 1;

    // ---- PhA: ks=0, all n; drain {A1,B1}(g+1); issue {A0,B0}(g+2) ----
    #pragma unroll
    for (int m = 0; m < 8; ++m)
      a[m] = *(const bf16x8*)(lds + REG_A(buf, 0) + rA + (unsigned)m * 1024u);
    #pragma unroll
    for (int n = 0; n < 4; ++n)
      b[n] = *(const bf16x8*)(lds + REG_B(buf, 0) + rB + (unsigned)n * 1024u);
    if (g >= 1 && g < 7) {
      drainA(REG_A(buf ^ 1, 1));
      drainB(REG_B(buf ^ 1, 1));
    }
    if (g + 2 < NT) {
      issueX(g + 2, 0);
      issueY(g + 2, 0);
    }
    __builtin_amdgcn_s_barrier();
    asm volatile("s_waitcnt lgkmcnt(0)" ::: "memory");
    __builtin_amdgcn_sched_barrier(0);
    __builtin_amdgcn_s_setprio(1);
    #pragma unroll
    for (int m = 0; m < 8; ++m)
      #pragma unroll
      for (int n = 0; n < 4; ++n)
        acc[m][n] = __builtin_amdgcn_mfma_f32_16x16x32_bf16(a[m], b[n],
                                                            acc[m][n], 0, 0, 0);
    __builtin_amdgcn_s_setprio(0);
    __builtin_amdgcn_s_barrier();

    // ---- PhB: ks=1, all n; drain {A0,B0}(g+2); issue {A1,B1}(g+2) ----
    #pragma unroll
    for (int m = 0; m < 8; ++m)
      a[m] = *(const bf16x8*)(lds + REG_A(buf, 1) + rA + (unsigned)m * 1024u);
    #pragma unroll
    for (int n = 0; n < 4; ++n)
      b[n] = *(const bf16x8*)(lds + REG_B(buf, 1) + rB + (unsigned)n * 1024u);
    if (g + 2 < NT) {
      drainA(REG_A(buf, 0));
      drainB(REG_B(buf, 0));
      issueX(g + 2, 1);
      issueY(g + 2, 1);
    }
    __builtin_amdgcn_s_barrier();
    asm volatile("s_waitcnt lgkmcnt(0)" ::: "memory");
    __builtin_amdgcn_sched_barrier(0);
    __builtin_amdgcn_s_setprio(1);
    #pragma unroll
    for (int m = 0; m < 8; ++m)
      #pragma unroll
      for (int n = 0; n < 4; ++n)
        acc[m][n] = __builtin_amdgcn_mfma_f32_16x16x32_bf16(a[m], b[n],
                                                            acc[m][n], 0, 0, 0);
    __builtin_amdgcn_s_setprio(0);
    __builtin_amdgcn_s_barrier();
  }

  // ---- norms: 4-lane row groups -> LDS publish ----
  nA0 += __shfl_xor(nA0, 1, 64); nA0 += __shfl_xor(nA0, 2, 64);
  nA1 += __shfl_xor(nA1, 1, 64); nA1 += __shfl_xor(nA1, 2, 64);
  nB0 += __shfl_xor(nB0, 1, 64); nB0 += __shfl_xor(nB0, 2, 64);
  nB1 += __shfl_xor(nB1, 1, 64); nB1 += __shfl_xor(nB1, 2, 64);
  if ((lane & 3) == 0) {
    const int j = lane >> 2;
    xs_l[wave * 32 + j] = nA0;
    xs_l[wave * 32 + 16 + j] = nA1;
    ys_l[wave * 32 + j] = nB0;
    ys_l[wave * 32 + 16 + j] = nB1;
  }
  asm volatile("s_waitcnt lgkmcnt(0)" ::: "memory");
  __builtin_amdgcn_s_barrier();

  // ---- epilogue: out = (||x||^2 + ||y||^2 - 2*dot) / 512 ----
  float ysv[4];
  #pragma unroll
  for (int n = 0; n < 4; ++n) ysv[n] = ys_l[wc * 64 + n * 16 + fr];

  #pragma unroll
  for (int m = 0; m < 8; ++m) {
    const int rl = wr * 128 + m * 16 + fq * 4;
    float xsv[4];
    #pragma unroll
    for (int r = 0; r < 4; ++r) xsv[r] = xs_l[rl + r];
    #pragma unroll
    for (int n = 0; n < 4; ++n) {
      const int col = bcol + wc * 64 + n * 16 + fr;
      #pragma unroll
      for (int r = 0; r < 4; ++r) {
        out[(size_t)(brow + rl + r) * NP + col] =
            (xsv[r] + ysv[n] - 2.0f * acc[m][n][r]) * (1.0f / 512.0f);
      }
    }
  }
}

extern "C" void kernel_launch(void* const* d_in, const int* in_sizes, int n_in,
                              void* d_out, int out_size, void* d_ws, size_t ws_size,
                              hipStream_t stream) {
  const float* X = (const float*)d_in[0];  // z_queries (8192, 512)
  const float* Y = (const float*)d_in[1];  // class_prototypes (4096, 512)
  float* out = (float*)d_out;              // (8192, 4096)
  fused_dist_kernel<<<512, 512, 0, stream>>>(X, Y, out);
}

// Round 9
// 68.475 us; speedup vs baseline: 1.4291x; 1.4266x over previous
//
#include <hip/hip_runtime.h>
#include <hip/hip_bf16.h>
#include <stdint.h>

typedef int v8i __attribute__((ext_vector_type(8)));
typedef float f32x4 __attribute__((ext_vector_type(4)));

#define NQ 8192
#define NP 4096
#define DD 512
#define NKT 4  // DD / 128

// ---------------------------------------------------------------------------
// Kernel 1: fp32 -> fp8(e4m3, OCP) panels + exact fp32 row norms.
// One wave per row; lane handles 8 consecutive cols -> 8 fp8 bytes (int2).
// ---------------------------------------------------------------------------
__global__ __launch_bounds__(256) void cvt_norms_kernel(
    const float* __restrict__ X, const float* __restrict__ Y,
    unsigned char* __restrict__ Xf8, unsigned char* __restrict__ Yf8,
    float* __restrict__ xsq, float* __restrict__ ysq) {
  const int wave = threadIdx.x >> 6;
  const int lane = threadIdx.x & 63;
  const int row = blockIdx.x * 4 + wave;  // 0..12287

  const float* src;
  unsigned char* dst;
  float* nrm;
  if (row < NQ) {
    src = X + (size_t)row * DD;
    dst = Xf8 + (size_t)row * DD;
    nrm = xsq + row;
  } else {
    const int r = row - NQ;
    src = Y + (size_t)r * DD;
    dst = Yf8 + (size_t)r * DD;
    nrm = ysq + r;
  }

  const float4 v0 = *(const float4*)(src + lane * 8);
  const float4 v1 = *(const float4*)(src + lane * 8 + 4);
  float s = v0.x * v0.x + v0.y * v0.y + v0.z * v0.z + v0.w * v0.w +
            v1.x * v1.x + v1.y * v1.y + v1.z * v1.z + v1.w * v1.w;

  int w0 = __builtin_amdgcn_cvt_pk_fp8_f32(v0.x, v0.y, 0, false);
  w0 = __builtin_amdgcn_cvt_pk_fp8_f32(v0.z, v0.w, w0, true);
  int w1 = __builtin_amdgcn_cvt_pk_fp8_f32(v1.x, v1.y, 0, false);
  w1 = __builtin_amdgcn_cvt_pk_fp8_f32(v1.z, v1.w, w1, true);
  int2 o; o.x = w0; o.y = w1;
  *(int2*)(dst + lane * 8) = o;

  #pragma unroll
  for (int off = 32; off; off >>= 1) s += __shfl_xor(s, off, 64);
  if (lane == 0) *nrm = s;
}

// ---------------------------------------------------------------------------
// Kernel 2: 256x256-tile NT GEMM in MX-fp8 (unit scales), BK=128 -> 4 K-tiles,
// 2 phases per K-tile (n-halves), 8 waves (2M x 4N). r2 barrier discipline.
//
// LDS (128 KiB): A [buf][256 rows][128B fp8], REG_A = buf*32768;
//                B same at +65536. Chunk swizzle: 16B chunk c (0..7) stored at
//                c ^ (row&7); inverse applied on global fp8 source address.
//
// MFMA: mfma_scale_f32_16x16x128_f8f6f4, fmt A=B=0 (e4m3), scales = 0x7F (1.0).
// Lane (fr=lane&15,fq=lane>>4): A frag = 32B at row(wr*128+m*16+fr),
// k = fq*32..+32 (chunks fq*2, fq*2+1). C/D: col=fr, row=fq*4+r (verified r1+).
//
// Ledger (4 loads per stage/thread). Load seq: P:A0(1-4) B0(5-8) A1(9-12) |
// Ph1(0):B1 | Ph2(0):A2 | Ph1(1):B2 | Ph2(1):A3 | Ph1(2):B3 | Ph2(2):A0' |
// Ph1(3):B0' | Ph2(3):A1'.  vmcnt(4) at prologue and at each Ph2 (after stage
// issue) certifies {A,B}(g+1) before Ph1(g+1)'s reads.  WAR: B(g+1)@Ph1(g)
// overwrites B(g-1), last read Ph2(g-1) (drained by lgkm(0) before that
// phase's MFMA; stage issue is after its end-barrier). A(g+2)@Ph2(g)
// overwrites A(g), last read Ph1(g) (same argument). Wrap tails g>=2 write
// regions with no remaining readers (checked).
// ---------------------------------------------------------------------------
__global__ __launch_bounds__(512, 1) void dist_gemm_kernel(
    const unsigned char* __restrict__ Xf8, const unsigned char* __restrict__ Yf8,
    const float* __restrict__ xsq, const float* __restrict__ ysq,
    float* __restrict__ out) {
  __shared__ __align__(128) unsigned char lds[131072];

  const int tid = threadIdx.x;
  const int wave = tid >> 6;
  const int lane = tid & 63;
  const int fr = lane & 15, fq = lane >> 4;
  const int wr = wave >> 2;  // 0..1: rows wr*128..+128
  const int wc = wave & 3;   // 0..3: cols wc*64..+64

  // XCD swizzle: 512 blocks, 64 contiguous wgids per XCD (bijective).
  const int bid = blockIdx.x;
  const int wgid = (bid & 7) * 64 + (bid >> 3);
  const int tileN = wgid & 15;
  const int tileM = wgid >> 4;
  const int brow = tileM * 256;
  const int bcol = tileN * 256;

#define REG_A(buf) ((unsigned)((buf)*32768))
#define REG_B(buf) ((unsigned)(65536 + (buf)*32768))

  // stage one 32KB K-tile panel (t in 0..3, masked); 4 loads/thread.
  auto stage = [&](int buf, int t, bool isA) {
    const unsigned char* base =
        isA ? (Xf8 + (size_t)brow * DD) : (Yf8 + (size_t)bcol * DD);
    const unsigned ldsbase = isA ? REG_A(buf) : REG_B(buf);
    const int tt = t & 3;
    #pragma unroll
    for (int i = 0; i < 4; ++i) {
      const unsigned P0 = (unsigned)(wave * 4 + i) * 1024u;  // wave-uniform
      const unsigned P = P0 + (unsigned)lane * 16u;          // lane's dst byte
      const unsigned row = P >> 7;
      const unsigned p = (P >> 4) & 7u;
      const unsigned char* src =
          base + (size_t)row * DD + tt * 128 + ((p ^ (row & 7u)) * 16u);
      __builtin_amdgcn_global_load_lds(
          (const __attribute__((address_space(1))) void*)src,
          (__attribute__((address_space(3))) void*)(lds + ldsbase + P0),
          16, 0, 0);
    }
  };

  // fragment read offsets (swizzled): chunk j of (row) at ((fq*2+j)^(fr&7))*16
  const unsigned c0 = (unsigned)(((fq * 2) ^ (fr & 7)) * 16);
  const unsigned c1 = (unsigned)(((fq * 2 + 1) ^ (fr & 7)) * 16);
  const unsigned baseA = (unsigned)((wr * 128 + fr) * 128);  // + m*2048
  const unsigned baseB = (unsigned)((wc * 64 + fr) * 128);   // + n*2048

  union U { int4 p[2]; v8i v; };

  f32x4 acc[8][4] = {};
  U a[8], b[4];

  // ---- prologue: A(0), B(0), A(1) = 12 loads ----
  stage(0, 0, true);
  stage(0, 0, false);
  stage(1, 1, true);
  asm volatile("s_waitcnt vmcnt(4)" ::: "memory");
  __builtin_amdgcn_s_barrier();

  #pragma unroll
  for (int g = 0; g < NKT; ++g) {
    const int buf = g & 1;

    // ---- Ph1: read a[0..7] + b0,b1; MFMA n=0,1 ----
    #pragma unroll
    for (int m = 0; m < 8; ++m) {
      a[m].p[0] = *(const int4*)(lds + REG_A(buf) + baseA + m * 2048 + c0);
      a[m].p[1] = *(const int4*)(lds + REG_A(buf) + baseA + m * 2048 + c1);
    }
    #pragma unroll
    for (int n = 0; n < 2; ++n) {
      b[n].p[0] = *(const int4*)(lds + REG_B(buf) + baseB + n * 2048 + c0);
      b[n].p[1] = *(const int4*)(lds + REG_B(buf) + baseB + n * 2048 + c1);
    }
    stage(buf ^ 1, g + 1, false);  // B(g+1)
    __builtin_amdgcn_s_barrier();
    asm volatile("s_waitcnt lgkmcnt(0)" ::: "memory");
    __builtin_amdgcn_sched_barrier(0);
    __builtin_amdgcn_s_setprio(1);
    #pragma unroll
    for (int m = 0; m < 8; ++m) {
      acc[m][0] = __builtin_amdgcn_mfma_scale_f32_16x16x128_f8f6f4(
          a[m].v, b[0].v, acc[m][0], 0, 0, 0, 0x7F, 0, 0x7F);
      acc[m][1] = __builtin_amdgcn_mfma_scale_f32_16x16x128_f8f6f4(
          a[m].v, b[1].v, acc[m][1], 0, 0, 0, 0x7F, 0, 0x7F);
    }
    __builtin_amdgcn_s_setprio(0);
    __builtin_amdgcn_s_barrier();

    // ---- Ph2: read b2,b3; MFMA n=2,3 ----
    #pragma unroll
    for (int n = 2; n < 4; ++n) {
      b[n].p[0] = *(const int4*)(lds + REG_B(buf) + baseB + n * 2048 + c0);
      b[n].p[1] = *(const int4*)(lds + REG_B(buf) + baseB + n * 2048 + c1);
    }
    stage(buf, g + 2, true);  // A(g+2)
    asm volatile("s_waitcnt vmcnt(4)" ::: "memory");
    __builtin_amdgcn_s_barrier();
    asm volatile("s_waitcnt lgkmcnt(0)" ::: "memory");
    __builtin_amdgcn_sched_barrier(0);
    __builtin_amdgcn_s_setprio(1);
    #pragma unroll
    for (int m = 0; m < 8; ++m) {
      acc[m][2] = __builtin_amdgcn_mfma_scale_f32_16x16x128_f8f6f4(
          a[m].v, b[2].v, acc[m][2], 0, 0, 0, 0x7F, 0, 0x7F);
      acc[m][3] = __builtin_amdgcn_mfma_scale_f32_16x16x128_f8f6f4(
          a[m].v, b[3].v, acc[m][3], 0, 0, 0, 0x7F, 0, 0x7F);
    }
    __builtin_amdgcn_s_setprio(0);
    __builtin_amdgcn_s_barrier();
  }

  // ---- epilogue: out[row][col] = (xsq[row] + ysq[col] - 2*acc) / 512 ----
  float ysv[4];
  #pragma unroll
  for (int n = 0; n < 4; ++n) ysv[n] = ysq[bcol + wc * 64 + n * 16 + fr];

  #pragma unroll
  for (int m = 0; m < 8; ++m) {
    const int rowb = brow + wr * 128 + m * 16 + fq * 4;
    float xsv[4];
    #pragma unroll
    for (int r = 0; r < 4; ++r) xsv[r] = xsq[rowb + r];
    #pragma unroll
    for (int n = 0; n < 4; ++n) {
      const int col = bcol + wc * 64 + n * 16 + fr;
      #pragma unroll
      for (int r = 0; r < 4; ++r) {
        out[(size_t)(rowb + r) * NP + col] =
            (xsv[r] + ysv[n] - 2.0f * acc[m][n][r]) * (1.0f / 512.0f);
      }
    }
  }
}

extern "C" void kernel_launch(void* const* d_in, const int* in_sizes, int n_in,
                              void* d_out, int out_size, void* d_ws, size_t ws_size,
                              hipStream_t stream) {
  const float* X = (const float*)d_in[0];  // z_queries (8192, 512)
  const float* Y = (const float*)d_in[1];  // class_prototypes (4096, 512)
  float* out = (float*)d_out;              // (8192, 4096)

  unsigned char* Xf8 = (unsigned char*)d_ws;       // 8192*512 fp8 (4MB)
  unsigned char* Yf8 = Xf8 + (size_t)NQ * DD;      // 4096*512 fp8 (2MB)
  float* xsq = (float*)(Yf8 + (size_t)NP * DD);    // 8192 f32
  float* ysq = xsq + NQ;                           // 4096 f32

  cvt_norms_kernel<<<(NQ + NP) / 4, 256, 0, stream>>>(X, Y, Xf8, Yf8, xsq, ysq);
  dist_gemm_kernel<<<(NQ / 256) * (NP / 256), 512, 0, stream>>>(Xf8, Yf8, xsq,
                                                                ysq, out);
}